// Round 6
// baseline (279.817 us; speedup 1.0000x reference)
//
#include <hip/hip_runtime.h>

// BCE loss reduction over (64,8,65536,1) fp32 pred/true.
// loss = -sum(t*max(log p,-100) + (1-t)*max(log(1-p),-100)) / (65536*64)
// log2-domain: bce_elem = lq + t*(lp-lq); scale by -ln2/4194304 at the end.
//
// R1-R3: compiler scheduler always collapses reg-based pipelines (VGPR
// 20/28/36) -> ~2 loads in flight/wave -> 2.6 TB/s cap; L3-resident runs at
// the same speed => per-wave request-concurrency bound, not HBM BW.
// R4/R5: raw-asm pipeline failed (compile error / garbage registers).
// R6: global_load_lds (direct-to-LDS DMA, m97-proven) double-buffered:
// loads have NO dest-VGPR dependency; each wave keeps 8 KB in flight;
// compute reads the landed tile from LDS. Compiler manages all waits.

#define LOG2_CLAMP -144.26950408889634f   // -100 / ln(2)
#define TILE 2048                          // floats per tensor per tile
#define THREADS 128                        // 2 waves per block

typedef __attribute__((address_space(1))) void GV;  // global
typedef __attribute__((address_space(3))) void LV;  // LDS

__device__ __forceinline__ void bce4_acc(float4 p, float4 t,
                                         float& sq, float& sd) {
    float lp, lq;
    lp = fmaxf(__log2f(p.x), LOG2_CLAMP);
    lq = fmaxf(__log2f(1.0f - p.x), LOG2_CLAMP);   // 1-p exact for p>=0.5
    sq += lq; sd = __builtin_fmaf(t.x, lp - lq, sd);
    lp = fmaxf(__log2f(p.y), LOG2_CLAMP);
    lq = fmaxf(__log2f(1.0f - p.y), LOG2_CLAMP);
    sq += lq; sd = __builtin_fmaf(t.y, lp - lq, sd);
    lp = fmaxf(__log2f(p.z), LOG2_CLAMP);
    lq = fmaxf(__log2f(1.0f - p.z), LOG2_CLAMP);
    sq += lq; sd = __builtin_fmaf(t.z, lp - lq, sd);
    lp = fmaxf(__log2f(p.w), LOG2_CLAMP);
    lq = fmaxf(__log2f(1.0f - p.w), LOG2_CLAMP);
    sq += lq; sd = __builtin_fmaf(t.w, lp - lq, sd);
}

__global__ __launch_bounds__(THREADS) void vertical_loss_kernel(
    const float* __restrict__ pf,
    const float* __restrict__ tf,
    float* __restrict__ out,
    int n, float final_scale)
{
    // 2 x (2 x 8 KB) double-buffered tiles = 32 KB -> 5 blocks/CU.
    __shared__ float Pb[2][TILE];
    __shared__ float Tb[2][TILE];

    const int tid  = threadIdx.x;
    const int wave = tid >> 6;      // 0..1
    const int lane = tid & 63;

    float sq = 0.0f, sd = 0.0f;

    const long long total = (long long)n;
    const int perBlockFloats = (int)(total / (long long)gridDim.x);
    const int iters = perBlockFloats / TILE;

    if ((total % ((long long)gridDim.x * TILE)) == 0 && iters > 0) {
        const long long blockBase = (long long)blockIdx.x * perBlockFloats;

        // Stage tile `it` into buffer b: per wave, 4 P-segments + 4
        // T-segments of 256 floats each; LDS dest is wave-uniform base,
        // HW deposits lane l's 16 B at base + l*16 (linear layout, no pad).
        auto stage = [&](int b, int it) {
            const float* gp = pf + blockBase + (long long)it * TILE;
            const float* gt = tf + blockBase + (long long)it * TILE;
            #pragma unroll
            for (int j = 0; j < 4; ++j) {
                const int s = wave * 4 + j;          // segment 0..7
                const int o = s * 256 + lane * 4;    // float offset in tile
                __builtin_amdgcn_global_load_lds((GV*)(gp + o),
                                                 (LV*)(&Pb[b][s * 256]),
                                                 16, 0, 0);
                __builtin_amdgcn_global_load_lds((GV*)(gt + o),
                                                 (LV*)(&Tb[b][s * 256]),
                                                 16, 0, 0);
            }
        };

        stage(0, 0);
        for (int it = 0; it < iters; ++it) {
            const int b = it & 1;
            if (it + 1 < iters) stage(b ^ 1, it + 1);   // prefetch next tile
            __syncthreads();                             // current tile landed
            const float4* P4 = (const float4*)Pb[b];
            const float4* T4 = (const float4*)Tb[b];
            #pragma unroll
            for (int k = 0; k < 4; ++k) {
                float4 p = P4[k * THREADS + tid];
                float4 t = T4[k * THREADS + tid];
                bce4_acc(p, t, sq, sd);
            }
            __syncthreads();   // tile consumed; buffer may be re-staged
        }
    } else {
        // Generic fallback (not taken for the bench shape).
        const float4* p4 = (const float4*)pf;
        const float4* t4 = (const float4*)tf;
        const int n4 = n >> 2;
        for (int i = (int)blockIdx.x * THREADS + tid; i < n4;
             i += (int)gridDim.x * THREADS)
            bce4_acc(p4[i], t4[i], sq, sd);
        if (blockIdx.x == 0 && tid == 0) {
            for (int i = n4 << 2; i < n; ++i) {
                float p = pf[i], t = tf[i];
                float lp = fmaxf(__log2f(p), LOG2_CLAMP);
                float lq = fmaxf(__log2f(1.0f - p), LOG2_CLAMP);
                sq += lq; sd = __builtin_fmaf(t, lp - lq, sd);
            }
        }
    }

    // Reduction: wave butterfly, then cross-wave via LDS (reuse Pb).
    float sum = sq + sd;
    #pragma unroll
    for (int off = 32; off > 0; off >>= 1)
        sum += __shfl_down(sum, off, 64);

    __syncthreads();                 // safe to reuse Pb as scratch
    if (lane == 0) Pb[0][wave] = sum;
    __syncthreads();
    if (tid == 0)
        atomicAdd(out, (Pb[0][0] + Pb[0][1]) * final_scale);
}

extern "C" void kernel_launch(void* const* d_in, const int* in_sizes, int n_in,
                              void* d_out, int out_size, void* d_ws, size_t ws_size,
                              hipStream_t stream) {
    const float* pred  = (const float*)d_in[0];
    const float* true_ = (const float*)d_in[1];
    float* out = (float*)d_out;

    int n = in_sizes[0];   // 33,554,432 floats per tensor
    // loss = -ln2 * (sq+sd)_total / (65536*64)
    float final_scale = -0.69314718055994531f / (65536.0f * 64.0f);

    // Harness re-poisons d_out with 0xAA before every launch — zero it.
    hipMemsetAsync(d_out, 0, sizeof(float), stream);

    // 1024 blocks x 128 threads, 32 KB LDS -> 5 blocks/CU (10 waves/CU),
    // all ~co-resident; 16 double-buffered tiles of 2048 floats per block.
    int blocks = 1024;
    vertical_loss_kernel<<<blocks, THREADS, 0, stream>>>(pred, true_, out, n, final_scale);
}

// Round 8
// 254.524 us; speedup vs baseline: 1.0994x; 1.0994x over previous
//
#include <hip/hip_runtime.h>

// BCE loss reduction over (64,8,65536,1) fp32 pred/true.
// loss = -sum(t*max(log p,-100) + (1-t)*max(log(1-p),-100)) / (65536*64)
// log2-domain: bce_elem = lq + t*(lp-lq); scale by -ln2/4194304 at the end.
//
// R1/R2/R3/R6 post-mortem: four structurally different kernels (naive
// grid-stride, 4x unroll, chunked+pipelined, LDS-DMA double-buffer; VGPR
// 20..68, occupancy 70%..20%) ALL land at ~103-108 us = ~2.6 TB/s read,
// including dispatches whose inputs are fully L3-resident. Per-wave MLP and
// memory source are ruled out => suspect per-CU L1 allocation/miss path for
// zero-reuse read streams (~4 B/cyc/CU). R8 = R7 with the compile fix
// (__builtin_nontemporal_load needs a clang ext_vector pointer, not
// HIP_vector_type): isolate ONE variable vs R3 — `nt` cache policy.

#define LOG2_CLAMP -144.26950408889634f   // -100 / ln(2)

typedef float vfloat4 __attribute__((ext_vector_type(4)));

__device__ __forceinline__ void bce4_acc(vfloat4 p, vfloat4 t,
                                         float& sq, float& sd) {
    float lp, lq;
    lp = fmaxf(__log2f(p.x), LOG2_CLAMP);
    lq = fmaxf(__log2f(1.0f - p.x), LOG2_CLAMP);   // 1-p exact for p>=0.5
    sq += lq; sd = __builtin_fmaf(t.x, lp - lq, sd);
    lp = fmaxf(__log2f(p.y), LOG2_CLAMP);
    lq = fmaxf(__log2f(1.0f - p.y), LOG2_CLAMP);
    sq += lq; sd = __builtin_fmaf(t.y, lp - lq, sd);
    lp = fmaxf(__log2f(p.z), LOG2_CLAMP);
    lq = fmaxf(__log2f(1.0f - p.z), LOG2_CLAMP);
    sq += lq; sd = __builtin_fmaf(t.z, lp - lq, sd);
    lp = fmaxf(__log2f(p.w), LOG2_CLAMP);
    lq = fmaxf(__log2f(1.0f - p.w), LOG2_CLAMP);
    sq += lq; sd = __builtin_fmaf(t.w, lp - lq, sd);
}

__global__ __launch_bounds__(256) void vertical_loss_kernel(
    const vfloat4* __restrict__ p4,
    const vfloat4* __restrict__ t4,
    float* __restrict__ out,
    int n4, float final_scale)
{
    float sq = 0.0f, sd = 0.0f;

    const int chunk = n4 / (int)gridDim.x;           // float4s per block
    const int steps = chunk / (int)blockDim.x;       // iterations per thread

    if ((chunk % (int)blockDim.x) == 0 && steps > 0) {
        // Block-contiguous tiles; the ONLY change vs R3 baseline: nt loads.
        const int stp = (int)blockDim.x;             // 256
        int i = (int)blockIdx.x * chunk + (int)threadIdx.x;
        #pragma unroll 4
        for (int s = 0; s < steps; ++s, i += stp) {
            vfloat4 p = __builtin_nontemporal_load(&p4[i]);
            vfloat4 t = __builtin_nontemporal_load(&t4[i]);
            bce4_acc(p, t, sq, sd);
        }
    } else {
        // Generic fallback (not taken for the bench shape).
        for (int i = (int)blockIdx.x * (int)blockDim.x + (int)threadIdx.x;
             i < n4; i += (int)gridDim.x * (int)blockDim.x) {
            vfloat4 p = __builtin_nontemporal_load(&p4[i]);
            vfloat4 t = __builtin_nontemporal_load(&t4[i]);
            bce4_acc(p, t, sq, sd);
        }
    }

    float sum = sq + sd;

    // wave (64-lane) reduction
    #pragma unroll
    for (int off = 32; off > 0; off >>= 1)
        sum += __shfl_down(sum, off, 64);

    __shared__ float wsum[4];  // 256 threads = 4 waves
    int wave = threadIdx.x >> 6;
    int lane = threadIdx.x & 63;
    if (lane == 0) wsum[wave] = sum;
    __syncthreads();

    if (threadIdx.x == 0) {
        float s = wsum[0] + wsum[1] + wsum[2] + wsum[3];
        atomicAdd(out, s * final_scale);  // device-scope by default on CDNA
    }
}

extern "C" void kernel_launch(void* const* d_in, const int* in_sizes, int n_in,
                              void* d_out, int out_size, void* d_ws, size_t ws_size,
                              hipStream_t stream) {
    const vfloat4* pred  = (const vfloat4*)d_in[0];
    const vfloat4* true_ = (const vfloat4*)d_in[1];
    float* out = (float*)d_out;

    int n  = in_sizes[0];   // 33,554,432
    int n4 = n / 4;         // 8,388,608 float4s
    // loss = -ln2 * (sq+sd)_total / (65536*64)
    float final_scale = -0.69314718055994531f / (65536.0f * 64.0f);

    // Harness re-poisons d_out with 0xAA before every launch — zero it.
    (void)hipMemsetAsync(d_out, 0, sizeof(float), stream);

    // 2048 blocks x 256 threads: contiguous 4096-float4 chunk per block,
    // 16 iterations/thread; 32 waves/CU.
    int blocks = 2048;
    vertical_loss_kernel<<<blocks, 256, 0, stream>>>(pred, true_, out, n4, final_scale);
}